// Round 5
// baseline (362.761 us; speedup 1.0000x reference)
//
#include <hip/hip_runtime.h>
#include <hip/hip_bf16.h>
#include <stdint.h>

// Qwen3 MLP with QDQ fake-quant, MI355X gfx950.
// M=8192 (B*S), H=1024, I=3072.
// R5: kgemm1 carries gate bf16-packed in 32 VGPRs across the up-pass
// (same thread owns same (m,n) in both passes) -> hbuf LDS deleted
// (51.7K -> 16.9K, 3 -> 4 blocks/CU), sigmoid moved to pass U with cheap
// sigma (amax-only approximation; exact u16-snapped chain stays in kmulo).

#define M_ROWS 8192
#define H_DIM 1024
#define I_DIM 3072

typedef unsigned short u16;
typedef unsigned int u32;
typedef __attribute__((ext_vector_type(8))) short bf16x8;
typedef __attribute__((ext_vector_type(4))) float f32x4;

__device__ __forceinline__ float bf2f(u16 v) { return __uint_as_float(((u32)v) << 16); }
__device__ __forceinline__ u16 f2bf(float f) {
  u32 u = __float_as_uint(f);
  u32 r = (u + 0x7fffu + ((u >> 16) & 1u)) >> 16;
  return (u16)r;
}
__device__ __forceinline__ float qdq16i(float x, float inv, float s) {
  float q = rintf(x * inv);
  q = fminf(fmaxf(q, -32768.f), 32767.f);
  return q * s;
}
// fixed u16 sigmoid grid (exact, used in kmulo)
__device__ __forceinline__ float sigq(float g) {
  float sig = __builtin_amdgcn_rcpf(1.f + __expf(-g));
  return fminf(fmaxf(rintf(sig * 65536.f), 0.f), 65535.f) * (1.f / 65536.f);
}
// cheap sigma for amax-only paths (skips u16 snap; |diff| <= 7.6e-6)
__device__ __forceinline__ float sig_approx(float g) {
  return __builtin_amdgcn_rcpf(1.f + __expf(-g));
}

// scal: u32[16][16]; sub-slot j of slot s at scal[j*16+s] (16 distinct 64B lines)
// slots: 0=x 1=up 2=gate 3=h 4=o
__device__ __forceinline__ float scale_read(const u32* __restrict__ scal, int s) {
  u32 m = 0;
#pragma unroll
  for (int j = 0; j < 16; ++j) m = max(m, scal[j * 16 + s]);
  return fmaxf(__uint_as_float(m) / 32767.f, 1e-12f);
}

__device__ __forceinline__ void load_lds16(const u16* g, u16* lds) {
  __builtin_amdgcn_global_load_lds(
      (const __attribute__((address_space(1))) u32*)g,
      (__attribute__((address_space(3))) u32*)lds, 16, 0, 0);
}

__device__ __forceinline__ void block_amax_atomic(float mx, u32* scal, int s) {
#pragma unroll
  for (int off = 32; off; off >>= 1) mx = fmaxf(mx, __shfl_xor(mx, off));
  __shared__ float red[4];
  const int lane = threadIdx.x & 63, wave = threadIdx.x >> 6;
  if (lane == 0) red[wave] = mx;
  __syncthreads();
  if (threadIdx.x == 0) {
    float m = fmaxf(fmaxf(red[0], red[1]), fmaxf(red[2], red[3]));
    atomicMax(scal + (blockIdx.x & 15) * 16 + s, __float_as_uint(m));
  }
}

// three amaxes with one barrier
__device__ __forceinline__ void block_amax3(float a, float b, float c, u32* scal,
                                            int sa, int sb, int sc) {
#pragma unroll
  for (int off = 32; off; off >>= 1) {
    a = fmaxf(a, __shfl_xor(a, off));
    b = fmaxf(b, __shfl_xor(b, off));
    c = fmaxf(c, __shfl_xor(c, off));
  }
  __shared__ float red3[3][4];
  const int lane = threadIdx.x & 63, wave = threadIdx.x >> 6;
  if (lane == 0) { red3[0][wave] = a; red3[1][wave] = b; red3[2][wave] = c; }
  __syncthreads();
  if (threadIdx.x == 0) {
    float ma = fmaxf(fmaxf(red3[0][0], red3[0][1]), fmaxf(red3[0][2], red3[0][3]));
    float mb = fmaxf(fmaxf(red3[1][0], red3[1][1]), fmaxf(red3[1][2], red3[1][3]));
    float mc = fmaxf(fmaxf(red3[2][0], red3[2][1]), fmaxf(red3[2][2], red3[2][3]));
    u32* base = scal + (blockIdx.x & 15) * 16;
    atomicMax(base + sa, __float_as_uint(ma));
    atomicMax(base + sb, __float_as_uint(mb));
    atomicMax(base + sc, __float_as_uint(mc));
  }
}

// ---------------- GEMM core (m97 structure) ----------------
// C[m,n] = sum_k A[m,k]*B[n,k]; row-major, row stride K (bf16 bits).
// 128x128 tile, BK=32, 4 waves each 64x64 via 4x4 MFMA 16x16x32.
// LDS swizzle: chunk q of row r holds granule q^((r>>1)&3) -> 2-way (free).
template <int K>
__device__ __forceinline__ void gemm_core(const u16* __restrict__ Ablk,
                                          const u16* __restrict__ Bblk,
                                          f32x4 acc[4][4], u16* smem) {
  u16* As = smem;          // 128*32
  u16* Bs = smem + 4096;   // 128*32
  const int tid = threadIdx.x;
  const int lane = tid & 63, wave = tid >> 6;
  const int wm = wave >> 1, wn = wave & 1;
  const int quad = lane >> 4, mrow = lane & 15;

  const int c0 = tid, c1 = tid + 256;
  const int r0 = c0 >> 2, g0 = ((c0 & 3) ^ ((r0 >> 1) & 3)) * 8;
  const int r1 = c1 >> 2, g1 = ((c1 & 3) ^ ((r1 >> 1) & 3)) * 8;
  const u16* a0 = Ablk + (size_t)r0 * K + g0;
  const u16* a1 = Ablk + (size_t)r1 * K + g1;
  const u16* b0 = Bblk + (size_t)r0 * K + g0;
  const u16* b1 = Bblk + (size_t)r1 * K + g1;
  u16* lA0 = &As[c0 * 8];
  u16* lA1 = &As[c1 * 8];
  u16* lB0 = &Bs[c0 * 8];
  u16* lB1 = &Bs[c1 * 8];

  int aoff[4], boff[4];
  const int lq = (quad ^ ((mrow >> 1) & 3)) * 8;
#pragma unroll
  for (int t = 0; t < 4; ++t) {
    aoff[t] = (wm * 64 + t * 16 + mrow) * 32 + lq;
    boff[t] = (wn * 64 + t * 16 + mrow) * 32 + lq;
  }

  for (int k0 = 0; k0 < K; k0 += 32) {
    __syncthreads();
    load_lds16(a0 + k0, lA0);
    load_lds16(a1 + k0, lA1);
    load_lds16(b0 + k0, lB0);
    load_lds16(b1 + k0, lB1);
    __syncthreads();
    bf16x8 af[4], bfr[4];
#pragma unroll
    for (int t = 0; t < 4; ++t) {
      af[t] = *(const bf16x8*)&As[aoff[t]];
      bfr[t] = *(const bf16x8*)&Bs[boff[t]];
    }
#pragma unroll
    for (int i = 0; i < 4; ++i)
#pragma unroll
      for (int j = 0; j < 4; ++j)
        acc[i][j] = __builtin_amdgcn_mfma_f32_16x16x32_bf16(af[i], bfr[j], acc[i][j], 0, 0, 0);
  }
}

// GEMM1: per block, same (m,n) region for gate then up.
// pass G: gate tile -> store gh, amax(gate)->2, keep bf16(gate) packed in regs.
// pass U: up tile -> store up, amax(up)->1; h=g*sig(g) approx -> amax(h)->3;
//         o=h*u -> amax(o)->4.
__global__ void __launch_bounds__(256) kgemm1(const u16* __restrict__ xq,
                                              const u16* __restrict__ wcat,
                                              u16* __restrict__ up, u16* __restrict__ gh,
                                              u32* __restrict__ scal) {
  __shared__ __align__(16) u16 smem[8192];
  const int tileN = blockIdx.x * 128;
  const int tileM = blockIdx.y * 128;
  const int lane = threadIdx.x & 63, wave = threadIdx.x >> 6;
  const int wm = wave >> 1, wn = wave & 1;
  const int rb = (lane >> 4) * 4, cb = lane & 15;  // C/D: row=(l>>4)*4+reg, col=l&15
  const int erow = lane >> 2, echk = lane & 3;
  u16* wbase = smem + wave * 1152;  // 16 rows * 72 (pad 8)
  const u16* rbase = wbase + erow * 72;
  const u16* Ablk = xq + (size_t)tileM * H_DIM;
  f32x4 acc[4][4];
  u32 gpack[32];  // 64 bf16 gate values packed 2/reg

  // ---------------- pass G (gate) ----------------
#pragma unroll
  for (int i = 0; i < 4; ++i)
#pragma unroll
    for (int j = 0; j < 4; ++j) acc[i][j] = (f32x4){0.f, 0.f, 0.f, 0.f};
  gemm_core<H_DIM>(Ablk, wcat + (size_t)(I_DIM + tileN) * H_DIM, acc, smem);
  {
    float mxg = 0.f;
#pragma unroll
    for (int i = 0; i < 4; ++i) {
      __syncthreads();
#pragma unroll
      for (int j = 0; j < 4; ++j)
#pragma unroll
        for (int r = 0; r < 4; ++r) {
          float g = acc[i][j][r];
          mxg = fmaxf(mxg, fabsf(g));
          u16 gb = f2bf(g);
          wbase[(rb + r) * 72 + j * 16 + cb] = gb;
          const int idx = i * 16 + j * 4 + r;
          if (r & 1) gpack[idx >> 1] |= ((u32)gb) << 16;
          else       gpack[idx >> 1] = (u32)gb;
        }
      __syncthreads();
      uint4 v0 = *(const uint4*)(rbase + echk * 8);
      uint4 v1 = *(const uint4*)(rbase + (echk + 4) * 8);
      size_t grow = (size_t)(tileM + wm * 64 + i * 16 + erow) * I_DIM + (tileN + wn * 64);
      *(uint4*)(gh + grow + echk * 8) = v0;
      *(uint4*)(gh + grow + (echk + 4) * 8) = v1;
    }
    block_amax_atomic(mxg, scal, 2);
  }

  // ---------------- pass U (up) ----------------
#pragma unroll
  for (int i = 0; i < 4; ++i)
#pragma unroll
    for (int j = 0; j < 4; ++j) acc[i][j] = (f32x4){0.f, 0.f, 0.f, 0.f};
  gemm_core<H_DIM>(Ablk, wcat + (size_t)tileN * H_DIM, acc, smem);
  {
    float mxu = 0.f, mxh = 0.f, mxo = 0.f;
#pragma unroll
    for (int i = 0; i < 4; ++i) {
      __syncthreads();
#pragma unroll
      for (int j = 0; j < 4; ++j)
#pragma unroll
        for (int r = 0; r < 4; ++r) {
          float u = acc[i][j][r];
          mxu = fmaxf(mxu, fabsf(u));
          wbase[(rb + r) * 72 + j * 16 + cb] = f2bf(u);
          const int idx = i * 16 + j * 4 + r;
          u16 gb = (r & 1) ? (u16)(gpack[idx >> 1] >> 16) : (u16)(gpack[idx >> 1] & 0xffffu);
          float g = bf2f(gb);
          float h = g * sig_approx(g);
          mxh = fmaxf(mxh, fabsf(h));
          mxo = fmaxf(mxo, fabsf(h * u));
        }
      __syncthreads();
      uint4 v0 = *(const uint4*)(rbase + echk * 8);
      uint4 v1 = *(const uint4*)(rbase + (echk + 4) * 8);
      size_t grow = (size_t)(tileM + wm * 64 + i * 16 + erow) * I_DIM + (tileN + wn * 64);
      *(uint4*)(up + grow + echk * 8) = v0;
      *(uint4*)(up + grow + (echk + 4) * 8) = v1;
    }
    block_amax3(mxu, mxh, mxo, scal, 1, 3, 4);
  }
}

// GEMM2: oq[8192,3072] x wdq[1024,3072]^T -> out fp32 [8192,1024]
__global__ void __launch_bounds__(256) kgemm2(const u16* __restrict__ oq,
                                              const u16* __restrict__ wdq,
                                              float* __restrict__ out) {
  __shared__ __align__(16) u16 smem[8192];
  const int tileN = blockIdx.x * 128;
  const int tileM = blockIdx.y * 128;
  f32x4 acc[4][4];
#pragma unroll
  for (int i = 0; i < 4; ++i)
#pragma unroll
    for (int j = 0; j < 4; ++j) acc[i][j] = (f32x4){0.f, 0.f, 0.f, 0.f};
  gemm_core<I_DIM>(oq + (size_t)tileM * I_DIM, wdq + (size_t)tileN * I_DIM, acc, smem);

  const int lane = threadIdx.x & 63, wave = threadIdx.x >> 6;
  const int wm = wave >> 1, wn = wave & 1;
  const int rb = (lane >> 4) * 4, cb = lane & 15;
#pragma unroll
  for (int i = 0; i < 4; ++i) {
#pragma unroll
    for (int j = 0; j < 4; ++j) {
      size_t base = (size_t)(tileM + wm * 64 + i * 16 + rb) * H_DIM +
                    (size_t)(tileN + wn * 64 + j * 16 + cb);
#pragma unroll
      for (int r = 0; r < 4; ++r) out[base + (size_t)r * H_DIM] = acc[i][j][r];
    }
  }
}

// ---------------- prep: absmax(x) (blocks 0..1023) + LPBQ dequant (rest) ----
__global__ void __launch_bounds__(256) kprep(const float* __restrict__ x,
                                             const float* __restrict__ wu,
                                             const float* __restrict__ wg,
                                             const float* __restrict__ wdn,
                                             u16* __restrict__ wcat, u16* __restrict__ wdq,
                                             u32* __restrict__ scal) {
  if (blockIdx.x < 1024) {
    const float4* x4 = (const float4*)x;
    const int n4 = (M_ROWS * H_DIM) / 4;
    float mx = 0.f;
    for (int i = blockIdx.x * 256 + threadIdx.x; i < n4; i += 1024 * 256) {
      float4 v = x4[i];
      mx = fmaxf(fmaxf(fabsf(v.x), fabsf(v.y)), fmaxf(fmaxf(fabsf(v.z), fabsf(v.w)), mx));
    }
    block_amax_atomic(mx, scal, 0);
    return;
  }
  const int gid = (blockIdx.x - 1024) * 256 + threadIdx.x;
  const int unit = gid >> 3, l8 = gid & 7;
  const float* src;
  u16* dst;
  int u;
  if (unit < 98304)       { src = wu;  dst = wcat;            u = unit; }
  else if (unit < 196608) { src = wg;  dst = wcat + 3145728;  u = unit - 98304; }
  else                    { src = wdn; dst = wdq;             u = unit - 196608; }
  const size_t off = (size_t)u * 32 + (size_t)l8 * 4;
  float4 v = *(const float4*)(src + off);
  float m = fmaxf(fmaxf(fabsf(v.x), fabsf(v.y)), fmaxf(fabsf(v.z), fabsf(v.w)));
  m = fmaxf(m, __shfl_xor(m, 1));
  m = fmaxf(m, __shfl_xor(m, 2));
  m = fmaxf(m, __shfl_xor(m, 4));
  const float s = fmaxf(m / 7.0f, 1e-12f);
  const float inv = 1.0f / s;
  float vv[4] = {v.x, v.y, v.z, v.w};
  u16 o[4];
#pragma unroll
  for (int e = 0; e < 4; ++e) {
    float q = rintf(vv[e] * inv);
    q = fminf(fmaxf(q, -8.f), 7.f);
    o[e] = f2bf(q * s);
  }
  *(ushort4*)(dst + off) = make_ushort4(o[0], o[1], o[2], o[3]);
}

__global__ void __launch_bounds__(256) kqdqx(const float4* __restrict__ x,
                                             ushort4* __restrict__ xq,
                                             const u32* __restrict__ scal) {
  const float s = scale_read(scal, 0);
  const float inv = 1.0f / s;
  const int i = blockIdx.x * 256 + threadIdx.x;
  float4 v = x[i];
  ushort4 o;
  o.x = f2bf(qdq16i(v.x, inv, s));
  o.y = f2bf(qdq16i(v.y, inv, s));
  o.z = f2bf(qdq16i(v.z, inv, s));
  o.w = f2bf(qdq16i(v.w, inv, s));
  xq[i] = o;
}

#define GH4 ((M_ROWS * I_DIM) / 8)
#define EW_BLOCKS 2048

// exact chain: g_q=qdq(g,sg); h=g_q*sigq(g_q); h_q=qdq(h,sh);
// o=h_q*qdq(u,su); oq=bf16(qdq(o,so)) -> gh (in place)
__global__ void __launch_bounds__(256) kmulo(uint4* __restrict__ gh, const uint4* __restrict__ up,
                                             u32* __restrict__ scal) {
  const float sg = scale_read(scal, 2), ig = 1.0f / sg;
  const float sh = scale_read(scal, 3), ih = 1.0f / sh;
  const float su = scale_read(scal, 1), iu = 1.0f / su;
  const float so = scale_read(scal, 4), io = 1.0f / so;
  for (int i = blockIdx.x * 256 + threadIdx.x; i < GH4; i += EW_BLOCKS * 256) {
    union { uint4 v; u16 us[8]; } a, b;
    a.v = gh[i];
    b.v = up[i];
#pragma unroll
    for (int e = 0; e < 8; ++e) {
      float g = qdq16i(bf2f(a.us[e]), ig, sg);
      float h = g * sigq(g);
      float o = qdq16i(h, ih, sh) * qdq16i(bf2f(b.us[e]), iu, su);
      a.us[e] = f2bf(qdq16i(o, io, so));
    }
    gh[i] = a.v;
  }
}

extern "C" void kernel_launch(void* const* d_in, const int* in_sizes, int n_in,
                              void* d_out, int out_size, void* d_ws, size_t ws_size,
                              hipStream_t stream) {
  (void)in_sizes; (void)n_in; (void)out_size; (void)ws_size;
  const float* x   = (const float*)d_in[0];
  const float* wg  = (const float*)d_in[1];
  const float* wu  = (const float*)d_in[2];
  const float* wdn = (const float*)d_in[3];
  float* out = (float*)d_out;
  char* ws = (char*)d_ws;

  u32* scal = (u32*)ws;
  u16* xq   = (u16*)(ws + 1024);                    // 8192*1024
  u16* wcat = xq + (size_t)M_ROWS * H_DIM;          // 6144*1024 (up rows, then gate rows)
  u16* wdq  = wcat + (size_t)2 * I_DIM * H_DIM;     // 1024*3072
  u16* up   = wdq + (size_t)H_DIM * I_DIM;          // 8192*3072
  u16* gh   = up + (size_t)M_ROWS * I_DIM;          // 8192*3072 (gate -> oq)

  hipMemsetAsync(scal, 0, 1024, stream);
  kprep<<<1024 + 9216, 256, 0, stream>>>(x, wu, wg, wdn, wcat, wdq, scal);
  kqdqx<<<(M_ROWS * H_DIM) / 4 / 256, 256, 0, stream>>>((const float4*)x, (ushort4*)xq, scal);
  kgemm1<<<dim3(24, 64), 256, 0, stream>>>(xq, wcat, up, gh, scal);
  kmulo<<<EW_BLOCKS, 256, 0, stream>>>((uint4*)gh, (const uint4*)up, scal);
  kgemm2<<<dim3(8, 64), 256, 0, stream>>>(gh, wdq, out);
}